// Round 2
// baseline (546.031 us; speedup 1.0000x reference)
//
#include <hip/hip_runtime.h>
#include <hip/hip_bf16.h>

#define B_N   8
#define T_N   32768
#define RESC  128
#define GATEC 256
#define CINC  80
#define NT    64
#define HALO  4
#define XROWS 68
#define XSTR  136   /* 68 dwords: stride mod 32 = 4 -> uniform b128 access */
#define CSTR  104   /* 52 dwords: stride mod 32 = 20 -> uniform b128 access */

#define AP1_ELEMS (16*12*512)  /* 98304 bf16 */
#define AP2_ELEMS (16*3*512)   /* 24576 */
#define AP3_ELEMS (16*4*512)   /* 32768 */

#define OFF_S ((size_t)B_N * RESC * T_N)  /* o first, then s */

typedef __attribute__((ext_vector_type(8))) short short8;
typedef __attribute__((ext_vector_type(4))) float f32x4;

__device__ __forceinline__ ushort f2bf(float f) {
  union { float f; unsigned int u; } c; c.f = f;
  unsigned int u = c.u;
  u += 0x7fffu + ((u >> 16) & 1u);   // RNE
  return (ushort)(u >> 16);
}
// packed pair convert (low = a, high = b)
__device__ __forceinline__ unsigned pkbf(float a, float b) {
  __hip_bfloat162 h = __float22bfloat162_rn(float2{a, b});
  unsigned u; __builtin_memcpy(&u, &h, 4); return u;
}

// ---------------------------------------------------------------------------
// Prep: weight-norm (fp32) -> bf16 -> pack into MFMA A/B-fragment order.
// frag[m = lane&15][k = (lane>>4)*8 + j]  (layout identical for A and B roles)
// ---------------------------------------------------------------------------
__global__ __launch_bounds__(256) void wn_pack_kernel(
    const float* __restrict__ conv_v, const float* __restrict__ conv_g,
    const float* __restrict__ lc_v,  const float* __restrict__ lc_g,
    const float* __restrict__ skip_v,const float* __restrict__ skip_g,
    const float* __restrict__ out_v, const float* __restrict__ out_g,
    ushort* __restrict__ Ap1, ushort* __restrict__ Ap2, ushort* __restrict__ Ap3) {
  const int o   = blockIdx.x;   // output channel 0..255
  const int tid = threadIdx.x;
  const int mtg = o >> 4, r = o & 15;
  __shared__ float red[256];

  // ---- conv: norm over 128*3 ----
  float s = 0.f;
  for (int e = tid; e < RESC * 3; e += 256) { float v = conv_v[o * RESC * 3 + e]; s += v * v; }
  red[tid] = s; __syncthreads();
  for (int off = 128; off > 0; off >>= 1) { if (tid < off) red[tid] += red[tid + off]; __syncthreads(); }
  const float csc = conv_g[o] / sqrtf(red[0]);
  __syncthreads();
  for (int e = tid; e < 384; e += 256) {
    const int ks = e >> 5, q = (e >> 3) & 3, j = e & 7;
    const int tap = ks >> 2, ci = (ks & 3) * 32 + q * 8 + j;
    Ap1[((mtg * 12 + ks) * 64 + q * 16 + r) * 8 + j] = f2bf(conv_v[(o * RESC + ci) * 3 + tap] * csc);
  }

  // ---- lc: norm over 80, pad K to 96 ----
  s = 0.f;
  for (int e = tid; e < CINC; e += 256) { float v = lc_v[o * CINC + e]; s += v * v; }
  red[tid] = s; __syncthreads();
  for (int off = 128; off > 0; off >>= 1) { if (tid < off) red[tid] += red[tid + off]; __syncthreads(); }
  const float lsc = lc_g[o] / sqrtf(red[0]);
  __syncthreads();
  for (int e = tid; e < 96; e += 256) {
    const int ks = e >> 5, q = (e >> 3) & 3, j = e & 7;
    const float wv = (e < CINC) ? lc_v[o * CINC + e] * lsc : 0.f;
    Ap2[((mtg * 3 + ks) * 64 + q * 16 + r) * 8 + j] = f2bf(wv);
  }

  // ---- skip (rows 0..127) / out (rows 128..255): norm over 128 ----
  const float* vrow = (o < 128) ? (skip_v + o * 128) : (out_v + (o - 128) * 128);
  const float  gg   = (o < 128) ? skip_g[o] : out_g[o - 128];
  s = 0.f;
  for (int e = tid; e < 128; e += 256) { float v = vrow[e]; s += v * v; }
  red[tid] = s; __syncthreads();
  for (int off = 128; off > 0; off >>= 1) { if (tid < off) red[tid] += red[tid + off]; __syncthreads(); }
  const float ssc = gg / sqrtf(red[0]);
  for (int e = tid; e < 128; e += 256) {
    const int ks = e >> 5, q = (e >> 3) & 3, j = e & 7;
    Ap3[((mtg * 4 + ks) * 64 + q * 16 + r) * 8 + j] = f2bf(vrow[e] * ssc);
  }
}

// ---------------------------------------------------------------------------
// Fused block. Grid 4096 = 8 batch x 512 time-tiles of 64. 256 thr = 4 waves.
// GEMM1/2: wave w owns gate rows [32w,32w+32) (tanh half) AND [128+32w,...)
// (sigmoid half) -> product in registers, only g goes to LDS.
// GEMM3 operand-swapped: D[m=t][n=ch] -> float4 epilogue.
// ---------------------------------------------------------------------------
__global__ __launch_bounds__(256) void fused_block_kernel(
    const float* __restrict__ x, const float* __restrict__ cond,
    const float* __restrict__ conv_b, const float* __restrict__ skip_b,
    const float* __restrict__ out_b,
    const ushort* __restrict__ Ap1, const ushort* __restrict__ Ap2,
    const ushort* __restrict__ Ap3,
    float* __restrict__ out) {
  const int tid  = threadIdx.x;
  const int w    = tid >> 6;
  const int lane = tid & 63;
  const int q    = lane >> 4;
  const int n    = lane & 15;
  const int blk  = blockIdx.x;
  const int b    = blk >> 9;
  const int t0   = (blk & 511) << 6;

  __shared__ ushort smem[XROWS * XSTR + NT * CSTR];  // 31808 B -> 5 blocks/CU
  ushort* xs = smem;                 // [68][136] x-tile (t-major, rows = t-(t0-4))
  ushort* cs = smem + XROWS * XSTR;  // [64][104] cond-tile
  ushort* gs = smem;                 // [64][136] g-tile (aliases xs after barrier)

  // ========== stage x tile: thread = 8ch x 4t block, b128 LDS writes =======
  {
    const int c0 = (tid & 15) << 3;
    const int tt = (tid >> 4) << 2;
    const float* xp = x + ((size_t)b * RESC + c0) * T_N + t0 + tt;
    float4 va[8];
#pragma unroll
    for (int rr = 0; rr < 8; ++rr) va[rr] = *(const float4*)(xp + (size_t)rr * T_N);
    const float* vf = (const float*)va;
#pragma unroll
    for (int i = 0; i < 4; ++i) {
      uint4 pkd;
      pkd.x = pkbf(vf[0 * 4 + i], vf[1 * 4 + i]);
      pkd.y = pkbf(vf[2 * 4 + i], vf[3 * 4 + i]);
      pkd.z = pkbf(vf[4 * 4 + i], vf[5 * 4 + i]);
      pkd.w = pkbf(vf[6 * 4 + i], vf[7 * 4 + i]);
      *(uint4*)&xs[(HALO + tt + i) * XSTR + c0] = pkd;
    }
  }
  // halo rows 0..3 = t0-4..t0-1 (zero at sequence start = causal left pad)
  if (tid < RESC) {
    float h0 = 0.f, h1 = 0.f, h2 = 0.f, h3 = 0.f;
    if (t0 > 0) {
      const float4 hv = *(const float4*)(x + ((size_t)b * RESC + tid) * T_N + t0 - 4);
      h0 = hv.x; h1 = hv.y; h2 = hv.z; h3 = hv.w;
    }
    xs[0 * XSTR + tid] = f2bf(h0);
    xs[1 * XSTR + tid] = f2bf(h1);
    xs[2 * XSTR + tid] = f2bf(h2);
    xs[3 * XSTR + tid] = f2bf(h3);
  }
  // ========== stage cond tile: 192 thr = 12 cblk x 16 tq; pad ch 80..95 ====
  if (tid < 192) {
    const int cb = tid % 12;
    const int tq = tid / 12;
    const int c0 = cb << 3;
    const int tt = tq << 2;
    if (cb < 10) {
      const float* cp = cond + ((size_t)b * CINC + c0) * T_N + t0 + tt;
      float4 va[8];
#pragma unroll
      for (int rr = 0; rr < 8; ++rr) va[rr] = *(const float4*)(cp + (size_t)rr * T_N);
      const float* vf = (const float*)va;
#pragma unroll
      for (int i = 0; i < 4; ++i) {
        uint4 pkd;
        pkd.x = pkbf(vf[0 * 4 + i], vf[1 * 4 + i]);
        pkd.y = pkbf(vf[2 * 4 + i], vf[3 * 4 + i]);
        pkd.z = pkbf(vf[4 * 4 + i], vf[5 * 4 + i]);
        pkd.w = pkbf(vf[6 * 4 + i], vf[7 * 4 + i]);
        *(uint4*)&cs[(tt + i) * CSTR + c0] = pkd;
      }
    } else {
#pragma unroll
      for (int i = 0; i < 4; ++i)
        *(uint4*)&cs[(tt + i) * CSTR + c0] = make_uint4(0, 0, 0, 0);
    }
  }
  __syncthreads();

  // ========== GEMM1 (conv, K=384) + GEMM2 (lc, K=96): a-half & b-half ======
  f32x4 aa[2][4], ab[2][4];
#pragma unroll
  for (int mt = 0; mt < 2; ++mt) {
    const float4 ca = *(const float4*)(conv_b + w * 32 + mt * 16 + q * 4);
    const float4 cb2 = *(const float4*)(conv_b + 128 + w * 32 + mt * 16 + q * 4);
#pragma unroll
    for (int nt = 0; nt < 4; ++nt) {
      aa[mt][nt] = (f32x4){ca.x, ca.y, ca.z, ca.w};
      ab[mt][nt] = (f32x4){cb2.x, cb2.y, cb2.z, cb2.w};
    }
  }
#pragma unroll
  for (int ks = 0; ks < 12; ++ks) {
    const int tap = ks >> 2;
    const int kc  = (ks & 3) << 5;
    short8 afa[2], afb[2], bfr[4];
#pragma unroll
    for (int mt = 0; mt < 2; ++mt) {
      afa[mt] = *(const short8*)(Ap1 + (((w * 2 + mt) * 12 + ks) << 9) + lane * 8);
      afb[mt] = *(const short8*)(Ap1 + (((8 + w * 2 + mt) * 12 + ks) << 9) + lane * 8);
    }
#pragma unroll
    for (int nt = 0; nt < 4; ++nt)
      bfr[nt] = *(const short8*)&xs[(nt * 16 + n + tap * 2) * XSTR + kc + q * 8];
#pragma unroll
    for (int mt = 0; mt < 2; ++mt)
#pragma unroll
      for (int nt = 0; nt < 4; ++nt) {
        aa[mt][nt] = __builtin_amdgcn_mfma_f32_16x16x32_bf16(afa[mt], bfr[nt], aa[mt][nt], 0, 0, 0);
        ab[mt][nt] = __builtin_amdgcn_mfma_f32_16x16x32_bf16(afb[mt], bfr[nt], ab[mt][nt], 0, 0, 0);
      }
  }
#pragma unroll
  for (int ks = 0; ks < 3; ++ks) {
    short8 afa[2], afb[2], bfr[4];
#pragma unroll
    for (int mt = 0; mt < 2; ++mt) {
      afa[mt] = *(const short8*)(Ap2 + (((w * 2 + mt) * 3 + ks) << 9) + lane * 8);
      afb[mt] = *(const short8*)(Ap2 + (((8 + w * 2 + mt) * 3 + ks) << 9) + lane * 8);
    }
#pragma unroll
    for (int nt = 0; nt < 4; ++nt)
      bfr[nt] = *(const short8*)&cs[(nt * 16 + n) * CSTR + (ks << 5) + q * 8];
#pragma unroll
    for (int mt = 0; mt < 2; ++mt)
#pragma unroll
      for (int nt = 0; nt < 4; ++nt) {
        aa[mt][nt] = __builtin_amdgcn_mfma_f32_16x16x32_bf16(afa[mt], bfr[nt], aa[mt][nt], 0, 0, 0);
        ab[mt][nt] = __builtin_amdgcn_mfma_f32_16x16x32_bf16(afb[mt], bfr[nt], ab[mt][nt], 0, 0, 0);
      }
  }
  __syncthreads();   // xs/cs reads done; gs may overwrite xs region

  // ========== g = tanh(a)*sigmoid(b) in registers -> gs =====================
#pragma unroll
  for (int mt = 0; mt < 2; ++mt)
#pragma unroll
    for (int nt = 0; nt < 4; ++nt) {
      const f32x4 va_ = aa[mt][nt];
      const f32x4 vb_ = ab[mt][nt];
      float g4[4];
#pragma unroll
      for (int i = 0; i < 4; ++i) {
        const float th = 1.f - 2.f / (__expf(2.f * va_[i]) + 1.f);
        const float sg = 1.f / (1.f + __expf(-vb_[i]));
        g4[i] = th * sg;
      }
      const uint2 pkd = make_uint2(pkbf(g4[0], g4[1]), pkbf(g4[2], g4[3]));
      *(uint2*)&gs[(nt * 16 + n) * XSTR + w * 32 + mt * 16 + q * 4] = pkd;
    }
  __syncthreads();

  // ========== GEMM3 (operand-swapped): D[m=t][n=ch] = g x W^T ==============
  {
    const int chbase = (w & 1) << 6;
    const float* bias = (w < 2) ? skip_b : out_b;
    f32x4 acc[4][4];
#pragma unroll
    for (int nt = 0; nt < 4; ++nt) {
      const float bv = bias[chbase + nt * 16 + n];
#pragma unroll
      for (int mt = 0; mt < 4; ++mt) acc[mt][nt] = (f32x4){bv, bv, bv, bv};
    }
#pragma unroll
    for (int ks = 0; ks < 4; ++ks) {
      short8 ag[4], bw[4];
#pragma unroll
      for (int mt = 0; mt < 4; ++mt)
        ag[mt] = *(const short8*)&gs[(mt * 16 + n) * XSTR + (ks << 5) + q * 8];
#pragma unroll
      for (int nt = 0; nt < 4; ++nt)
        bw[nt] = *(const short8*)(Ap3 + (((w * 4 + nt) * 4 + ks) << 9) + lane * 8);
#pragma unroll
      for (int mt = 0; mt < 4; ++mt)
#pragma unroll
        for (int nt = 0; nt < 4; ++nt)
          acc[mt][nt] = __builtin_amdgcn_mfma_f32_16x16x32_bf16(ag[mt], bw[nt], acc[mt][nt], 0, 0, 0);
    }

    // ========== epilogue: float4 stores; residual float4 loads =============
#pragma unroll
    for (int mt = 0; mt < 4; ++mt)
#pragma unroll
      for (int nt = 0; nt < 4; ++nt) {
        const int ch = chbase + nt * 16 + n;
        const int t  = t0 + mt * 16 + q * 4;
        const f32x4 v = acc[mt][nt];
        if (w < 2) {  // skip output s
          *(float4*)(out + OFF_S + ((size_t)(b * RESC + ch)) * T_N + t) =
              make_float4(v[0], v[1], v[2], v[3]);
        } else {      // o = out-proj + residual
          const float4 xr = *(const float4*)(x + ((size_t)(b * RESC + ch)) * T_N + t);
          *(float4*)(out + ((size_t)(b * RESC + ch)) * T_N + t) =
              make_float4(v[0] + xr.x, v[1] + xr.y, v[2] + xr.z, v[3] + xr.w);
        }
      }
  }
}

extern "C" void kernel_launch(void* const* d_in, const int* in_sizes, int n_in,
                              void* d_out, int out_size, void* d_ws, size_t ws_size,
                              hipStream_t stream) {
  const float* x      = (const float*)d_in[0];
  const float* cond   = (const float*)d_in[1];
  const float* conv_v = (const float*)d_in[2];
  const float* conv_g = (const float*)d_in[3];
  const float* conv_b = (const float*)d_in[4];
  const float* lc_v   = (const float*)d_in[5];
  const float* lc_g   = (const float*)d_in[6];
  const float* skip_v = (const float*)d_in[7];
  const float* skip_g = (const float*)d_in[8];
  const float* skip_b = (const float*)d_in[9];
  const float* out_v  = (const float*)d_in[10];
  const float* out_g  = (const float*)d_in[11];
  const float* out_b  = (const float*)d_in[12];

  ushort* Ap1 = (ushort*)d_ws;
  ushort* Ap2 = Ap1 + AP1_ELEMS;
  ushort* Ap3 = Ap2 + AP2_ELEMS;

  hipLaunchKernelGGL(wn_pack_kernel, dim3(256), dim3(256), 0, stream,
                     conv_v, conv_g, lc_v, lc_g, skip_v, skip_g, out_v, out_g,
                     Ap1, Ap2, Ap3);
  hipLaunchKernelGGL(fused_block_kernel, dim3(4096), dim3(256), 0, stream,
                     x, cond, conv_b, skip_b, out_b, Ap1, Ap2, Ap3, (float*)d_out);
}